// Round 10
// baseline (90.818 us; speedup 1.0000x reference)
//
#include <hip/hip_runtime.h>

// Problem constants
#define BATCH 8
#define IMH 96
#define IMW 96
#define CH 32
#define NKP 21
#define TW 32             // tile width
#define TH 8              // tile height
#define HW 34             // halo width
#define HH 10             // halo height
#define NPIXH 340         // HW*HH
#define NSTRIP 11         // ceil(340/32)
#define NSLOT 352         // NSTRIP*32
#define FPITCH 40         // bf16 per pixel in LDS (80 B stride)
#define NGRP 3            // keypoints per block
#define FBLK 1152         // f-precompute blocks (73728 px / 64)

typedef __bf16 bf16x8 __attribute__((ext_vector_type(8)));
typedef __bf16 bf16x4 __attribute__((ext_vector_type(4)));
typedef float  f32x4  __attribute__((ext_vector_type(4)));
typedef float  f32x16 __attribute__((ext_vector_type(16)));

static __device__ inline f32x16 mfma32(bf16x8 a, bf16x8 b, f32x16 c) {
    return __builtin_amdgcn_mfma_f32_32x32x16_bf16(a, b, c, 0, 0, 0);
}

// ---------------- Prep: f = relu(x@w2+b2) (blocks 0..1151) + weight pack (1152..1172) ----
// 32x32x16 A-frag for lane l (m=l&31 out-ch, hi=l>>5): frag[kh][j] = W^T[m][k], k=kh*16+hi*8+j
__global__ void __launch_bounds__(64)
prep_kernel(const float* __restrict__ x,
            const float* __restrict__ w2, const float* __restrict__ b2,
            const float* __restrict__ wa, const float* __restrict__ wb,
            const float* __restrict__ Wp,
            __bf16* __restrict__ fout, float* __restrict__ fsum_out,
            __bf16* __restrict__ wfrag, float* __restrict__ wv)
{
    const int bx = blockIdx.x;
    const int lane = threadIdx.x;
    if (bx < FBLK) {
        const int gp = bx * 64 + lane;
        const float* xp = x + (size_t)gp * CH;
        float xv[CH];
        #pragma unroll
        for (int e = 0; e < CH; e += 4) {
            float4 v = *(const float4*)(xp + e);
            xv[e] = v.x; xv[e+1] = v.y; xv[e+2] = v.z; xv[e+3] = v.w;
        }
        float f[CH];
        #pragma unroll
        for (int c = 0; c < CH; ++c) f[c] = b2[c];
        #pragma unroll
        for (int e = 0; e < CH; ++e) {
            const float xe = xv[e];
            const float* wr = w2 + e * CH;
            #pragma unroll
            for (int c = 0; c < CH; ++c) f[c] = fmaf(xe, wr[c], f[c]);
        }
        float fs = 0.f;
        #pragma unroll
        for (int c = 0; c < CH; ++c) { f[c] = fmaxf(f[c], 0.f); fs += f[c]; }
        #pragma unroll
        for (int q = 0; q < 4; ++q) {
            bf16x8 v;
            #pragma unroll
            for (int j = 0; j < 8; ++j) v[j] = (__bf16)f[q * 8 + j];
            *(bf16x8*)&fout[(size_t)gp * CH + q * 8] = v;
        }
        fsum_out[gp] = fs;
    } else {
        const int n = bx - FBLK;             // 0..20
        const int m = lane & 31, hi = lane >> 5;
        const float* wan = wa + n * CH * CH;
        #pragma unroll
        for (int kh = 0; kh < 2; ++kh) {
            bf16x8 v;
            #pragma unroll
            for (int j = 0; j < 8; ++j)
                v[j] = (__bf16)wan[(kh * 16 + hi * 8 + j) * CH + m];
            *(bf16x8*)&wfrag[(((size_t)n * 20 + kh) * 64 + lane) * 8] = v;
        }
        const float* wbn = wb + (size_t)n * 9 * CH * CH;
        for (int t = 0; t < 9; ++t)
            #pragma unroll
            for (int kh = 0; kh < 2; ++kh) {
                bf16x8 v;
                #pragma unroll
                for (int j = 0; j < 8; ++j)
                    v[j] = (__bf16)wbn[(t * CH + kh * 16 + hi * 8 + j) * CH + m];
                *(bf16x8*)&wfrag[(((size_t)n * 20 + 2 + t * 2 + kh) * 64 + lane) * 8] = v;
            }
        if (lane < CH) {
            const float* wp = Wp + (n * CH + lane) * CH;
            float s = 0.f;
            #pragma unroll
            for (int d = 0; d < CH; ++d) s += wp[d];
            wv[n * CH + lane] = s;
        }
    }
}

// Build a 16-reg f32 C-frag from a 32-float array: reg r -> ch (r&3)+8*(r>>2)+4*hi
static __device__ inline f32x16 load_cfrag(const float* p, int hi) {
    f32x16 out;
    #pragma unroll
    for (int q = 0; q < 4; ++q) {
        f32x4 v = *(const f32x4*)&p[q * 8 + hi * 4];
        #pragma unroll
        for (int r = 0; r < 4; ++r) out[q * 4 + r] = v[r];
    }
    return out;
}

// ---------------- Main: 32-wide tile, 32x32x16 MFMA, 4 independent acc chains ----
__global__ void __launch_bounds__(256, 4)
ckp_mfma8_kernel(const __bf16* __restrict__ fws, const float* __restrict__ fsum_ws,
                 const __bf16* __restrict__ wfrag, const float* __restrict__ wvws,
                 const float* __restrict__ ba, const float* __restrict__ bb,
                 float* __restrict__ out)
{
    __shared__ __bf16 sH[NSLOT * FPITCH];   // 28,160 B

    const int tid   = threadIdx.x;
    const int tile  = blockIdx.x;          // 0..35
    const int b     = blockIdx.y;          // 0..7
    const int nbase = blockIdx.z * NGRP;   // 0,3,..,18
    const int ty0   = (tile % (IMH / TH)) * TH;   // 12 y-tiles
    const int tx0   = (tile / (IMH / TH)) * TW;   // 3 x-tiles

    const int lane = tid & 63;
    const int w    = tid >> 6;            // wave 0..3
    const int c5   = lane & 31;           // pixel / out-col
    const int hi   = lane >> 5;           // k/ch sub-group
    const int w2r  = w * 2;               // this wave's first output row

    // ---- hoisted strip addressing: strips t = w + 4i ----
    int voff[3]; unsigned dmask = 0;
    #pragma unroll
    for (int i = 0; i < 3; ++i) {
        const int t  = w + 4 * i;
        const int px = t * 32 + c5;
        const int hy = px / HW, hx = px % HW;
        const int Y  = ty0 + hy - 1, X = tx0 + hx - 1;
        const bool dv = (px < NPIXH) & (Y >= 0) & (Y < IMH) & (X >= 0) & (X < IMW);
        const int Yc = min(max(Y, 0), IMH - 1), Xc = min(max(X, 0), IMW - 1);
        voff[i] = ((b * IMH + Yc) * IMW + Xc) * CH + hi * 8;   // + kh*16 at use
        dmask |= (dv ? 1u : 0u) << i;
    }
    // h-write LDS offsets (elems): px*40 + 4*hi (+8q at store)
    int wo[3];
    #pragma unroll
    for (int i = 0; i < 3; ++i) wo[i] = ((w + 4 * i) * 32 + c5) * FPITCH + 4 * hi;
    // conv read offsets per halo row hr = w2r + h4 (elems): (hr*34 + c5)*40 + 8*hi
    int ro[4];
    #pragma unroll
    for (int h4 = 0; h4 < 4; ++h4) ro[h4] = ((w2r + h4) * HW + c5) * FPITCH + 8 * hi;
    // fsum for this wave's 2 output rows
    float fs2[2];
    #pragma unroll
    for (int ri = 0; ri < 2; ++ri)
        fs2[ri] = fsum_ws[(b * IMH + ty0 + w2r + ri) * IMW + tx0 + c5];

    for (int ni = 0; ni < NGRP; ++ni) {
        const int n = nbase + ni;
        const __bf16* wf = wfrag + (size_t)n * 20 * 64 * 8;
        const bf16x8 wa0 = *(const bf16x8*)&wf[((size_t)0 * 64 + lane) * 8];
        const bf16x8 wa1 = *(const bf16x8*)&wf[((size_t)1 * 64 + lane) * 8];
        const f32x16 baf = load_cfrag(ba + n * CH, hi);

        if (ni) __syncthreads();   // prev conv reads done before overwrite

        // ---- h-phase: h = relu(wa^T @ f + ba), one 32-px strip per MFMA pair ----
        #pragma unroll
        for (int i = 0; i < 3; ++i) {
            const int t = w + 4 * i;               // wave-uniform
            if (t < NSTRIP) {
                bf16x8 f0 = *(const bf16x8*)&fws[voff[i]];
                bf16x8 f1 = *(const bf16x8*)&fws[voff[i] + 16];
                f32x16 a = mfma32(wa0, f0, baf);
                a = mfma32(wa1, f1, a);
                const bool dv = (dmask >> i) & 1;
                #pragma unroll
                for (int q = 0; q < 4; ++q) {
                    bf16x4 hq;
                    #pragma unroll
                    for (int r = 0; r < 4; ++r)
                        hq[r] = dv ? (__bf16)fmaxf(a[q * 4 + r], 0.f) : (__bf16)0.f;
                    *(bf16x4*)&sH[wo[i] + 8 * q] = hq;
                }
            }
        }
        __syncthreads();

        // ---- conv: 4 INDEPENDENT acc chains (row x kh), 9 MFMA each ----
        const f32x16 bbf = load_cfrag(bb + n * CH, hi);
        const f32x16 zz = {0.f,0.f,0.f,0.f,0.f,0.f,0.f,0.f,
                           0.f,0.f,0.f,0.f,0.f,0.f,0.f,0.f};
        f32x16 acc[2][2];
        acc[0][0] = bbf; acc[0][1] = zz;    // kh halves are K-partials, summed later
        acc[1][0] = bbf; acc[1][1] = zz;
        #pragma unroll
        for (int dx = 0; dx < 3; ++dx) {
            bf16x8 wt[3][2];
            #pragma unroll
            for (int dy = 0; dy < 3; ++dy)
                #pragma unroll
                for (int kh = 0; kh < 2; ++kh)
                    wt[dy][kh] = *(const bf16x8*)&wf[((size_t)(2 + (dy * 3 + dx) * 2 + kh) * 64 + lane) * 8];
            #pragma unroll
            for (int h4 = 0; h4 < 4; ++h4) {
                const int ad = ro[h4] + dx * FPITCH;
                bf16x8 B0 = *(const bf16x8*)&sH[ad];
                bf16x8 B1 = *(const bf16x8*)&sH[ad + 16];
                #pragma unroll
                for (int dy = 0; dy < 3; ++dy) {
                    const int ri = h4 - dy;        // output row = w2r + ri
                    if (ri >= 0 && ri < 2) {
                        acc[ri][0] = mfma32(wt[dy][0], B0, acc[ri][0]);
                        acc[ri][1] = mfma32(wt[dy][1], B1, acc[ri][1]);
                    }
                }
            }
        }

        // ---- epilogue: merge kh partials; lsum = relu(g).wv; one shfl; store ----
        const f32x16 wvf = load_cfrag(wvws + n * CH, hi);
        #pragma unroll
        for (int ri = 0; ri < 2; ++ri) {
            const f32x16 a = acc[ri][0] + acc[ri][1];
            float s = 0.f;
            #pragma unroll
            for (int r = 0; r < 16; ++r)
                s += fmaxf(a[r], 0.f) * wvf[r];
            s += __shfl_xor(s, 32);
            if (hi == 0) {
                const int gp = (b * IMH + ty0 + w2r + ri) * IMW + tx0 + c5;
                out[(size_t)gp * NKP + n] = s + fs2[ri];
            }
        }
    }
}

// ---------------- Fallback (R1 fused fp32 VALU kernel) ----------------
#define PITCH 33
#define FTILE 16
#define FHALO 18
__global__ void __launch_bounds__(256)
ckp_fused_kernel(const float* __restrict__ x,
                 const float* __restrict__ w2, const float* __restrict__ b2,
                 const float* __restrict__ wa, const float* __restrict__ ba,
                 const float* __restrict__ wb, const float* __restrict__ bb,
                 const float* __restrict__ Wp,
                 float* __restrict__ out)
{
    __shared__ float sH[FHALO * FHALO * PITCH];
    __shared__ float sFsum[FTILE * FTILE];
    __shared__ float sWv[CH];

    const int tid  = threadIdx.x;
    const int tile = blockIdx.x;
    const int b    = blockIdx.y;
    const int n    = blockIdx.z;
    const int ty0  = (tile / (IMW / FTILE)) * FTILE;
    const int tx0  = (tile % (IMW / FTILE)) * FTILE;

    if (tid < CH) {
        const float* wp = Wp + (n * CH + tid) * CH;
        float s = 0.f;
        #pragma unroll
        for (int d = 0; d < CH; ++d) s += wp[d];
        sWv[tid] = s;
    }
    const float* wan = wa + n * CH * CH;
    const float* ban = ba + n * CH;

    for (int p = tid; p < FHALO * FHALO; p += 256) {
        const int hy = p / FHALO, hx = p % FHALO;
        const int Y = ty0 + hy - 1, X = tx0 + hx - 1;
        float* dst = &sH[p * PITCH];
        if (Y >= 0 && Y < IMH && X >= 0 && X < IMW) {
            const float* xp = x + (((size_t)b * IMH + Y) * IMW + X) * CH;
            float xv[CH];
            #pragma unroll
            for (int e = 0; e < CH; e += 4) {
                float4 v = *(const float4*)(xp + e);
                xv[e] = v.x; xv[e+1] = v.y; xv[e+2] = v.z; xv[e+3] = v.w;
            }
            float f[CH];
            #pragma unroll
            for (int c = 0; c < CH; ++c) f[c] = b2[c];
            #pragma unroll
            for (int e = 0; e < CH; ++e) {
                const float xe = xv[e];
                const float* wr = w2 + e * CH;
                #pragma unroll
                for (int c = 0; c < CH; ++c) f[c] = fmaf(xe, wr[c], f[c]);
            }
            float fs = 0.f;
            #pragma unroll
            for (int c = 0; c < CH; ++c) { f[c] = fmaxf(f[c], 0.f); fs += f[c]; }
            if (hy >= 1 && hy <= FTILE && hx >= 1 && hx <= FTILE)
                sFsum[(hy - 1) * FTILE + (hx - 1)] = fs;
            float h[CH];
            #pragma unroll
            for (int c = 0; c < CH; ++c) h[c] = ban[c];
            #pragma unroll
            for (int e = 0; e < CH; ++e) {
                const float fe = f[e];
                const float* wr = wan + e * CH;
                #pragma unroll
                for (int c = 0; c < CH; ++c) h[c] = fmaf(fe, wr[c], h[c]);
            }
            #pragma unroll
            for (int c = 0; c < CH; ++c) dst[c] = fmaxf(h[c], 0.f);
        } else {
            #pragma unroll
            for (int c = 0; c < CH; ++c) dst[c] = 0.f;
        }
    }
    __syncthreads();

    const int iy = tid / FTILE, ix = tid % FTILE;
    const float* wbn = wb + n * 9 * CH * CH;
    const float* bbn = bb + n * CH;
    float g[CH];
    #pragma unroll
    for (int c = 0; c < CH; ++c) g[c] = bbn[c];
    for (int dy = 0; dy < 3; ++dy) {
        for (int dx = 0; dx < 3; ++dx) {
            const float* hrow = &sH[((iy + dy) * FHALO + (ix + dx)) * PITCH];
            const float* wr0 = wbn + (dy * 3 + dx) * CH * CH;
            #pragma unroll
            for (int e = 0; e < CH; ++e) {
                const float hv = hrow[e];
                const float* wr = wr0 + e * CH;
                #pragma unroll
                for (int c = 0; c < CH; ++c) g[c] = fmaf(hv, wr[c], g[c]);
            }
        }
    }
    float lsum = 0.f;
    #pragma unroll
    for (int c = 0; c < CH; ++c) lsum = fmaf(fmaxf(g[c], 0.f), sWv[c], lsum);
    const int Y = ty0 + iy, X = tx0 + ix;
    out[(((size_t)b * IMH + Y) * IMW + X) * NKP + n] = sFsum[tid] + lsum;
}

extern "C" void kernel_launch(void* const* d_in, const int* in_sizes, int n_in,
                              void* d_out, int out_size, void* d_ws, size_t ws_size,
                              hipStream_t stream) {
    const float* x  = (const float*)d_in[0];
    const float* w2 = (const float*)d_in[1];
    const float* b2 = (const float*)d_in[2];
    const float* wa = (const float*)d_in[3];
    const float* ba = (const float*)d_in[4];
    const float* wb = (const float*)d_in[5];
    const float* bb = (const float*)d_in[6];
    const float* Wp = (const float*)d_in[7];
    float* out = (float*)d_out;

    const size_t npix     = (size_t)BATCH * IMH * IMW;                  // 73728
    const size_t f_bytes  = npix * CH * sizeof(__bf16);                 // 4,718,592
    const size_t fs_bytes = npix * sizeof(float);                       //   294,912
    const size_t wf_bytes = (size_t)NKP * 20 * 64 * 8 * sizeof(__bf16); //   430,080
    const size_t wv_bytes = (size_t)NKP * CH * sizeof(float);           //     2,688
    const size_t need = f_bytes + fs_bytes + wf_bytes + wv_bytes;

    if (ws_size >= need) {
        __bf16* f_ws    = (__bf16*)d_ws;
        float*  fsum_ws = (float*)((char*)d_ws + f_bytes);
        __bf16* wf_ws   = (__bf16*)((char*)d_ws + f_bytes + fs_bytes);
        float*  wv_ws   = (float*)((char*)d_ws + f_bytes + fs_bytes + wf_bytes);

        prep_kernel<<<dim3(FBLK + NKP), dim3(64), 0, stream>>>(
            x, w2, b2, wa, wb, Wp, f_ws, fsum_ws, wf_ws, wv_ws);
        dim3 grid((IMW / TW) * (IMH / TH), BATCH, NKP / NGRP); // 36 x 8 x 7
        ckp_mfma8_kernel<<<grid, dim3(256), 0, stream>>>(f_ws, fsum_ws, wf_ws, wv_ws, ba, bb, out);
    } else {
        dim3 grid((IMW / FTILE) * (IMH / FTILE), BATCH, NKP);
        ckp_fused_kernel<<<grid, dim3(256), 0, stream>>>(x, w2, b2, wa, ba, wb, bb, Wp, out);
    }
}

// Round 11
// 61.057 us; speedup vs baseline: 1.4874x; 1.4874x over previous
//
#include <hip/hip_runtime.h>

// Problem constants
#define BATCH 8
#define IMH 96
#define IMW 96
#define CH 32
#define NKP 21
#define TW 32             // tile width
#define TH 8              // tile height
#define HW 34             // halo width
#define HH 10             // halo height
#define NPIXH 340         // HW*HH
#define NSTRIP 11         // ceil(340/32)
#define NSLOT 352         // NSTRIP*32
#define FPITCH 40         // bf16 per pixel in LDS (80 B stride)
#define NGRP 3            // keypoints per block
#define FBLK 1152         // f-precompute blocks (73728 px / 64)

typedef __bf16 bf16x8 __attribute__((ext_vector_type(8)));
typedef __bf16 bf16x4 __attribute__((ext_vector_type(4)));
typedef float  f32x4  __attribute__((ext_vector_type(4)));
typedef float  f32x16 __attribute__((ext_vector_type(16)));

static __device__ inline f32x16 mfma32(bf16x8 a, bf16x8 b, f32x16 c) {
    return __builtin_amdgcn_mfma_f32_32x32x16_bf16(a, b, c, 0, 0, 0);
}

// ---------------- Prep: f = relu(x@w2+b2) (blocks 0..1151) + weight pack (1152..1172) ----
// 32x32x16 A-frag for lane l (m=l&31 out-ch, hi=l>>5): frag[kh][j] = W^T[m][k], k=kh*16+hi*8+j
__global__ void __launch_bounds__(64)
prep_kernel(const float* __restrict__ x,
            const float* __restrict__ w2, const float* __restrict__ b2,
            const float* __restrict__ wa, const float* __restrict__ wb,
            const float* __restrict__ Wp,
            __bf16* __restrict__ fout, float* __restrict__ fsum_out,
            __bf16* __restrict__ wfrag, float* __restrict__ wv)
{
    const int bx = blockIdx.x;
    const int lane = threadIdx.x;
    if (bx < FBLK) {
        const int gp = bx * 64 + lane;
        const float* xp = x + (size_t)gp * CH;
        float xv[CH];
        #pragma unroll
        for (int e = 0; e < CH; e += 4) {
            float4 v = *(const float4*)(xp + e);
            xv[e] = v.x; xv[e+1] = v.y; xv[e+2] = v.z; xv[e+3] = v.w;
        }
        float f[CH];
        #pragma unroll
        for (int c = 0; c < CH; ++c) f[c] = b2[c];
        #pragma unroll
        for (int e = 0; e < CH; ++e) {
            const float xe = xv[e];
            const float* wr = w2 + e * CH;
            #pragma unroll
            for (int c = 0; c < CH; ++c) f[c] = fmaf(xe, wr[c], f[c]);
        }
        float fs = 0.f;
        #pragma unroll
        for (int c = 0; c < CH; ++c) { f[c] = fmaxf(f[c], 0.f); fs += f[c]; }
        #pragma unroll
        for (int q = 0; q < 4; ++q) {
            bf16x8 v;
            #pragma unroll
            for (int j = 0; j < 8; ++j) v[j] = (__bf16)f[q * 8 + j];
            *(bf16x8*)&fout[(size_t)gp * CH + q * 8] = v;
        }
        fsum_out[gp] = fs;
    } else {
        const int n = bx - FBLK;             // 0..20
        const int m = lane & 31, hi = lane >> 5;
        const float* wan = wa + n * CH * CH;
        #pragma unroll
        for (int kh = 0; kh < 2; ++kh) {
            bf16x8 v;
            #pragma unroll
            for (int j = 0; j < 8; ++j)
                v[j] = (__bf16)wan[(kh * 16 + hi * 8 + j) * CH + m];
            *(bf16x8*)&wfrag[(((size_t)n * 20 + kh) * 64 + lane) * 8] = v;
        }
        const float* wbn = wb + (size_t)n * 9 * CH * CH;
        for (int t = 0; t < 9; ++t)
            #pragma unroll
            for (int kh = 0; kh < 2; ++kh) {
                bf16x8 v;
                #pragma unroll
                for (int j = 0; j < 8; ++j)
                    v[j] = (__bf16)wbn[(t * CH + kh * 16 + hi * 8 + j) * CH + m];
                *(bf16x8*)&wfrag[(((size_t)n * 20 + 2 + t * 2 + kh) * 64 + lane) * 8] = v;
            }
        if (lane < CH) {
            const float* wp = Wp + (n * CH + lane) * CH;
            float s = 0.f;
            #pragma unroll
            for (int d = 0; d < CH; ++d) s += wp[d];
            wv[n * CH + lane] = s;
        }
    }
}

// Build a 16-reg f32 C-frag from a 32-float array: reg r -> ch (r&3)+8*(r>>2)+4*hi
static __device__ inline f32x16 load_cfrag(const float* p, int hi) {
    f32x16 out;
    #pragma unroll
    for (int q = 0; q < 4; ++q) {
        f32x4 v = *(const f32x4*)&p[q * 8 + hi * 4];
        #pragma unroll
        for (int r = 0; r < 4; ++r) out[q * 4 + r] = v[r];
    }
    return out;
}

// ---------------- Main: 32-wide tile, 32x32x16 MFMA, 4 independent acc chains ----
// launch_bounds(256,3): 170-VGPR cap -- acc[2][2] (64) + wt (24) + misc fits, no spill.
__global__ void __launch_bounds__(256, 3)
ckp_mfma9_kernel(const __bf16* __restrict__ fws, const float* __restrict__ fsum_ws,
                 const __bf16* __restrict__ wfrag, const float* __restrict__ wvws,
                 const float* __restrict__ ba, const float* __restrict__ bb,
                 float* __restrict__ out)
{
    __shared__ __bf16 sH[NSLOT * FPITCH];   // 28,160 B

    const int tid   = threadIdx.x;
    const int tile  = blockIdx.x;          // 0..35
    const int b     = blockIdx.y;          // 0..7
    const int nbase = blockIdx.z * NGRP;   // 0,3,..,18
    const int ty0   = (tile % (IMH / TH)) * TH;   // 12 y-tiles
    const int tx0   = (tile / (IMH / TH)) * TW;   // 3 x-tiles

    const int lane = tid & 63;
    const int w    = tid >> 6;            // wave 0..3
    const int c5   = lane & 31;           // pixel / out-col
    const int hi   = lane >> 5;           // k/ch sub-group
    const int w2r  = w * 2;               // this wave's first output row

    // ---- hoisted strip addressing: strips t = w + 4i ----
    int voff[3]; unsigned dmask = 0;
    #pragma unroll
    for (int i = 0; i < 3; ++i) {
        const int t  = w + 4 * i;
        const int px = t * 32 + c5;
        const int hy = px / HW, hx = px % HW;
        const int Y  = ty0 + hy - 1, X = tx0 + hx - 1;
        const bool dv = (px < NPIXH) & (Y >= 0) & (Y < IMH) & (X >= 0) & (X < IMW);
        const int Yc = min(max(Y, 0), IMH - 1), Xc = min(max(X, 0), IMW - 1);
        voff[i] = ((b * IMH + Yc) * IMW + Xc) * CH + hi * 8;   // + kh*16 at use
        dmask |= (dv ? 1u : 0u) << i;
    }
    // h-write LDS offsets (elems): px*40 + 4*hi (+8q at store)
    int wo[3];
    #pragma unroll
    for (int i = 0; i < 3; ++i) wo[i] = ((w + 4 * i) * 32 + c5) * FPITCH + 4 * hi;
    // conv read offsets per halo row hr = w2r + h4 (elems): (hr*34 + c5)*40 + 8*hi
    int ro[4];
    #pragma unroll
    for (int h4 = 0; h4 < 4; ++h4) ro[h4] = ((w2r + h4) * HW + c5) * FPITCH + 8 * hi;
    // fsum for this wave's 2 output rows
    float fs2[2];
    #pragma unroll
    for (int ri = 0; ri < 2; ++ri)
        fs2[ri] = fsum_ws[(b * IMH + ty0 + w2r + ri) * IMW + tx0 + c5];

    for (int ni = 0; ni < NGRP; ++ni) {
        const int n = nbase + ni;
        const __bf16* wf = wfrag + (size_t)n * 20 * 64 * 8;
        const bf16x8 wa0 = *(const bf16x8*)&wf[((size_t)0 * 64 + lane) * 8];
        const bf16x8 wa1 = *(const bf16x8*)&wf[((size_t)1 * 64 + lane) * 8];
        const f32x16 baf = load_cfrag(ba + n * CH, hi);

        if (ni) __syncthreads();   // prev conv reads done before overwrite

        // ---- h-phase: h = relu(wa^T @ f + ba), one 32-px strip per MFMA pair ----
        #pragma unroll
        for (int i = 0; i < 3; ++i) {
            const int t = w + 4 * i;               // wave-uniform
            if (t < NSTRIP) {
                bf16x8 f0 = *(const bf16x8*)&fws[voff[i]];
                bf16x8 f1 = *(const bf16x8*)&fws[voff[i] + 16];
                f32x16 a = mfma32(wa0, f0, baf);
                a = mfma32(wa1, f1, a);
                const bool dv = (dmask >> i) & 1;
                #pragma unroll
                for (int q = 0; q < 4; ++q) {
                    bf16x4 hq;
                    #pragma unroll
                    for (int r = 0; r < 4; ++r)
                        hq[r] = dv ? (__bf16)fmaxf(a[q * 4 + r], 0.f) : (__bf16)0.f;
                    *(bf16x4*)&sH[wo[i] + 8 * q] = hq;
                }
            }
        }
        __syncthreads();

        // ---- conv: 4 INDEPENDENT acc chains (row x kh), 9 MFMA each ----
        const f32x16 bbf = load_cfrag(bb + n * CH, hi);
        const f32x16 zz = {0.f,0.f,0.f,0.f,0.f,0.f,0.f,0.f,
                           0.f,0.f,0.f,0.f,0.f,0.f,0.f,0.f};
        f32x16 acc[2][2];
        acc[0][0] = bbf; acc[0][1] = zz;    // kh halves are K-partials, summed later
        acc[1][0] = bbf; acc[1][1] = zz;
        #pragma unroll
        for (int dx = 0; dx < 3; ++dx) {
            bf16x8 wt[3][2];
            #pragma unroll
            for (int dy = 0; dy < 3; ++dy)
                #pragma unroll
                for (int kh = 0; kh < 2; ++kh)
                    wt[dy][kh] = *(const bf16x8*)&wf[((size_t)(2 + (dy * 3 + dx) * 2 + kh) * 64 + lane) * 8];
            #pragma unroll
            for (int h4 = 0; h4 < 4; ++h4) {
                const int ad = ro[h4] + dx * FPITCH;
                bf16x8 B0 = *(const bf16x8*)&sH[ad];
                bf16x8 B1 = *(const bf16x8*)&sH[ad + 16];
                #pragma unroll
                for (int dy = 0; dy < 3; ++dy) {
                    const int ri = h4 - dy;        // output row = w2r + ri
                    if (ri >= 0 && ri < 2) {
                        acc[ri][0] = mfma32(wt[dy][0], B0, acc[ri][0]);
                        acc[ri][1] = mfma32(wt[dy][1], B1, acc[ri][1]);
                    }
                }
            }
        }

        // ---- epilogue: merge kh partials; lsum = relu(g).wv; one shfl; store ----
        const f32x16 wvf = load_cfrag(wvws + n * CH, hi);
        #pragma unroll
        for (int ri = 0; ri < 2; ++ri) {
            const f32x16 a = acc[ri][0] + acc[ri][1];
            float s = 0.f;
            #pragma unroll
            for (int r = 0; r < 16; ++r)
                s += fmaxf(a[r], 0.f) * wvf[r];
            s += __shfl_xor(s, 32);
            if (hi == 0) {
                const int gp = (b * IMH + ty0 + w2r + ri) * IMW + tx0 + c5;
                out[(size_t)gp * NKP + n] = s + fs2[ri];
            }
        }
    }
}

// ---------------- Fallback (R1 fused fp32 VALU kernel) ----------------
#define PITCH 33
#define FTILE 16
#define FHALO 18
__global__ void __launch_bounds__(256)
ckp_fused_kernel(const float* __restrict__ x,
                 const float* __restrict__ w2, const float* __restrict__ b2,
                 const float* __restrict__ wa, const float* __restrict__ ba,
                 const float* __restrict__ wb, const float* __restrict__ bb,
                 const float* __restrict__ Wp,
                 float* __restrict__ out)
{
    __shared__ float sH[FHALO * FHALO * PITCH];
    __shared__ float sFsum[FTILE * FTILE];
    __shared__ float sWv[CH];

    const int tid  = threadIdx.x;
    const int tile = blockIdx.x;
    const int b    = blockIdx.y;
    const int n    = blockIdx.z;
    const int ty0  = (tile / (IMW / FTILE)) * FTILE;
    const int tx0  = (tile % (IMW / FTILE)) * FTILE;

    if (tid < CH) {
        const float* wp = Wp + (n * CH + tid) * CH;
        float s = 0.f;
        #pragma unroll
        for (int d = 0; d < CH; ++d) s += wp[d];
        sWv[tid] = s;
    }
    const float* wan = wa + n * CH * CH;
    const float* ban = ba + n * CH;

    for (int p = tid; p < FHALO * FHALO; p += 256) {
        const int hy = p / FHALO, hx = p % FHALO;
        const int Y = ty0 + hy - 1, X = tx0 + hx - 1;
        float* dst = &sH[p * PITCH];
        if (Y >= 0 && Y < IMH && X >= 0 && X < IMW) {
            const float* xp = x + (((size_t)b * IMH + Y) * IMW + X) * CH;
            float xv[CH];
            #pragma unroll
            for (int e = 0; e < CH; e += 4) {
                float4 v = *(const float4*)(xp + e);
                xv[e] = v.x; xv[e+1] = v.y; xv[e+2] = v.z; xv[e+3] = v.w;
            }
            float f[CH];
            #pragma unroll
            for (int c = 0; c < CH; ++c) f[c] = b2[c];
            #pragma unroll
            for (int e = 0; e < CH; ++e) {
                const float xe = xv[e];
                const float* wr = w2 + e * CH;
                #pragma unroll
                for (int c = 0; c < CH; ++c) f[c] = fmaf(xe, wr[c], f[c]);
            }
            float fs = 0.f;
            #pragma unroll
            for (int c = 0; c < CH; ++c) { f[c] = fmaxf(f[c], 0.f); fs += f[c]; }
            if (hy >= 1 && hy <= FTILE && hx >= 1 && hx <= FTILE)
                sFsum[(hy - 1) * FTILE + (hx - 1)] = fs;
            float h[CH];
            #pragma unroll
            for (int c = 0; c < CH; ++c) h[c] = ban[c];
            #pragma unroll
            for (int e = 0; e < CH; ++e) {
                const float fe = f[e];
                const float* wr = wan + e * CH;
                #pragma unroll
                for (int c = 0; c < CH; ++c) h[c] = fmaf(fe, wr[c], h[c]);
            }
            #pragma unroll
            for (int c = 0; c < CH; ++c) dst[c] = fmaxf(h[c], 0.f);
        } else {
            #pragma unroll
            for (int c = 0; c < CH; ++c) dst[c] = 0.f;
        }
    }
    __syncthreads();

    const int iy = tid / FTILE, ix = tid % FTILE;
    const float* wbn = wb + n * 9 * CH * CH;
    const float* bbn = bb + n * CH;
    float g[CH];
    #pragma unroll
    for (int c = 0; c < CH; ++c) g[c] = bbn[c];
    for (int dy = 0; dy < 3; ++dy) {
        for (int dx = 0; dx < 3; ++dx) {
            const float* hrow = &sH[((iy + dy) * FHALO + (ix + dx)) * PITCH];
            const float* wr0 = wbn + (dy * 3 + dx) * CH * CH;
            #pragma unroll
            for (int e = 0; e < CH; ++e) {
                const float hv = hrow[e];
                const float* wr = wr0 + e * CH;
                #pragma unroll
                for (int c = 0; c < CH; ++c) g[c] = fmaf(hv, wr[c], g[c]);
            }
        }
    }
    float lsum = 0.f;
    #pragma unroll
    for (int c = 0; c < CH; ++c) lsum = fmaf(fmaxf(g[c], 0.f), sWv[c], lsum);
    const int Y = ty0 + iy, X = tx0 + ix;
    out[(((size_t)b * IMH + Y) * IMW + X) * NKP + n] = sFsum[tid] + lsum;
}

extern "C" void kernel_launch(void* const* d_in, const int* in_sizes, int n_in,
                              void* d_out, int out_size, void* d_ws, size_t ws_size,
                              hipStream_t stream) {
    const float* x  = (const float*)d_in[0];
    const float* w2 = (const float*)d_in[1];
    const float* b2 = (const float*)d_in[2];
    const float* wa = (const float*)d_in[3];
    const float* ba = (const float*)d_in[4];
    const float* wb = (const float*)d_in[5];
    const float* bb = (const float*)d_in[6];
    const float* Wp = (const float*)d_in[7];
    float* out = (float*)d_out;

    const size_t npix     = (size_t)BATCH * IMH * IMW;                  // 73728
    const size_t f_bytes  = npix * CH * sizeof(__bf16);                 // 4,718,592
    const size_t fs_bytes = npix * sizeof(float);                       //   294,912
    const size_t wf_bytes = (size_t)NKP * 20 * 64 * 8 * sizeof(__bf16); //   430,080
    const size_t wv_bytes = (size_t)NKP * CH * sizeof(float);           //     2,688
    const size_t need = f_bytes + fs_bytes + wf_bytes + wv_bytes;

    if (ws_size >= need) {
        __bf16* f_ws    = (__bf16*)d_ws;
        float*  fsum_ws = (float*)((char*)d_ws + f_bytes);
        __bf16* wf_ws   = (__bf16*)((char*)d_ws + f_bytes + fs_bytes);
        float*  wv_ws   = (float*)((char*)d_ws + f_bytes + fs_bytes + wf_bytes);

        prep_kernel<<<dim3(FBLK + NKP), dim3(64), 0, stream>>>(
            x, w2, b2, wa, wb, Wp, f_ws, fsum_ws, wf_ws, wv_ws);
        dim3 grid((IMW / TW) * (IMH / TH), BATCH, NKP / NGRP); // 36 x 8 x 7
        ckp_mfma9_kernel<<<grid, dim3(256), 0, stream>>>(f_ws, fsum_ws, wf_ws, wv_ws, ba, bb, out);
    } else {
        dim3 grid((IMW / FTILE) * (IMH / FTILE), BATCH, NKP);
        ckp_fused_kernel<<<grid, dim3(256), 0, stream>>>(x, w2, b2, wa, ba, wb, bb, Wp, out);
    }
}